// Round 4
// baseline (231.895 us; speedup 1.0000x reference)
//
#include <hip/hip_runtime.h>
#include <math.h>

#define EPS_F 1e-7f

constexpr int Bc = 32, Tc = 8192, Kc = 16;
constexpr int ROWS  = Bc * Tc;            // 262144 rows, 16 K-slots each
constexpr int BLOCK = 256;
constexpr int NBLK  = ROWS / BLOCK;       // 1024 blocks, 1 row per thread

typedef unsigned long long u64;

// One thread owns one full row (16 K-slots):
//  - oracle first-match table (32 contracts x 4-bit nibble) built thread-
//    locally by folding k DESCENDING with overwrite => smallest matching k
//    wins == reference argmax(first match). No shuffles, no LDS, no DMA.
//  - zero data reuse across threads => no LDS staging (pure overhead here).
//  - loads: per array 4 x vec4 at 64B/lane stride; the 4 consecutive vec4s
//    of each array hit the same cache lines => L1 absorbs the stride.
//  - __launch_bounds__(256, 2): 256-VGPR budget (no spills; ~112 VGPRs of
//    phase-B loads live at peak). 8 waves/CU; ILP (28 loads in flight/wave
//    = 28KB) covers HBM latency per Little's law (~9KB/CU needed).
__global__ __launch_bounds__(BLOCK, 2) void loss_main(
    const float* __restrict__ trig,
    const float* __restrict__ valp,
    const float* __restrict__ clog,
    const float* __restrict__ wscore,
    const int*   __restrict__ live,
    const int*   __restrict__ cid,
    const float* __restrict__ ofire,
    const int*   __restrict__ ocan,
    const float* __restrict__ ovalid,
    const float* __restrict__ oshw,
    const int*   __restrict__ ocid,
    float* __restrict__ part)            // [NBLK][6]
{
  const int tid = threadIdx.x;
  const int row = blockIdx.x * BLOCK + tid;       // exact: NBLK*BLOCK == ROWS
  const size_t o64  = (size_t)row * 64;           // 16 slots * 4B
  const size_t o192 = (size_t)row * 192;          // 16 slots * 3 * 4B

  // ---- phase A: oracle arrays -> first-match table (2 x u64, 32 nibbles)
  int4 oc[4]; int4 cc[4]; float4 ff[4]; float4 vv[4];
  #pragma unroll
  for (int j = 0; j < 4; ++j) {
    oc[j] = *(const int4*)  ((const char*)ocid   + o64 + j * 16);
    cc[j] = *(const int4*)  ((const char*)ocan   + o64 + j * 16);
    ff[j] = *(const float4*)((const char*)ofire  + o64 + j * 16);
    vv[j] = *(const float4*)((const char*)ovalid + o64 + j * 16);
  }

  u64 tblLo = 0ull, tblHi = 0ull, fndLo = 0ull, fndHi = 0ull;
  #pragma unroll
  for (int j = 3; j >= 0; --j) {
    const int   ocs[4] = {oc[j].x, oc[j].y, oc[j].z, oc[j].w};
    const int   ccs[4] = {cc[j].x, cc[j].y, cc[j].z, cc[j].w};
    const float ffs[4] = {ff[j].x, ff[j].y, ff[j].z, ff[j].w};
    const float vvs[4] = {vv[j].x, vv[j].y, vv[j].z, vv[j].w};
    #pragma unroll
    for (int s = 3; s >= 0; --s) {                // descending k overall
      const unsigned c   = (unsigned)ocs[s] & 31u;
      const unsigned sh  = (c & 15u) * 4u;
      const bool     isLo = c < 16u;
      const unsigned nib = (unsigned)ffs[s] | ((unsigned)vvs[s] << 1) |
                           ((unsigned)ccs[s] << 2);
      const u64 msk = 0xFull << sh;
      const u64 add = (u64)nib << sh;
      tblLo = isLo ? ((tblLo & ~msk) | add) : tblLo;
      tblHi = isLo ? tblHi : ((tblHi & ~msk) | add);
      fndLo |= isLo ? msk : 0ull;
      fndHi |= isLo ? 0ull : msk;
    }
  }

  // ---- phase B: model arrays + losses (thread-local, fully unrolled)
  int4 cd[4]; int4 lm[4]; float4 ph[4]; float4 pq[4]; float4 cl[12];
  #pragma unroll
  for (int j = 0; j < 4; ++j) {
    cd[j] = *(const int4*)  ((const char*)cid  + o64 + j * 16);
    lm[j] = *(const int4*)  ((const char*)live + o64 + j * 16);
    ph[j] = *(const float4*)((const char*)trig + o64 + j * 16);
    pq[j] = *(const float4*)((const char*)valp + o64 + j * 16);
  }
  #pragma unroll
  for (int j = 0; j < 12; ++j) {
    cl[j] = *(const float4*)((const char*)clog + o192 + j * 16);
  }
  const float wx = wscore[row];
  const float wy = oshw[row];

  // flatten (constant indices only -> stays in registers)
  int   cds[16], lms[16];
  float phs[16], pqs[16], F[48];
  #pragma unroll
  for (int j = 0; j < 4; ++j) {
    cds[4*j+0]=cd[j].x; cds[4*j+1]=cd[j].y; cds[4*j+2]=cd[j].z; cds[4*j+3]=cd[j].w;
    lms[4*j+0]=lm[j].x; lms[4*j+1]=lm[j].y; lms[4*j+2]=lm[j].z; lms[4*j+3]=lm[j].w;
    phs[4*j+0]=ph[j].x; phs[4*j+1]=ph[j].y; phs[4*j+2]=ph[j].z; phs[4*j+3]=ph[j].w;
    pqs[4*j+0]=pq[j].x; pqs[4*j+1]=pq[j].y; pqs[4*j+2]=pq[j].z; pqs[4*j+3]=pq[j].w;
  }
  #pragma unroll
  for (int j = 0; j < 12; ++j) {
    F[4*j+0]=cl[j].x; F[4*j+1]=cl[j].y; F[4*j+2]=cl[j].z; F[4*j+3]=cl[j].w;
  }

  float a0 = 0.f, a1 = 0.f, a2 = 0.f, a3 = 0.f, a4 = 0.f;
  #pragma unroll
  for (int k = 0; k < 16; ++k) {
    const unsigned c  = (unsigned)cds[k] & 31u;
    const unsigned sh = (c & 15u) * 4u;
    const bool isLo   = c < 16u;
    const bool fnd = (c != 0u) &&
                     ((((isLo ? fndLo : fndHi) >> sh) & 1ull) != 0ull);
    unsigned nib = (unsigned)(((isLo ? tblLo : tblHi) >> sh)) & 15u;
    nib = fnd ? nib : 0u;
    const float fire_t = (float)(nib & 1u);
    const float val_t  = (float)((nib >> 1) & 1u);
    const int   can_t  = (int)(nib >> 2);

    const float m = lms[k] ? 1.f : 0.f;

    const float p  = fminf(fmaxf(phs[k], EPS_F), 1.f - EPS_F);
    const float bf = -__logf((fire_t != 0.f) ? p : 1.f - p);
    const float q  = fminf(fmaxf(pqs[k], EPS_F), 1.f - EPS_F);
    const float bv = -__logf((val_t != 0.f) ? q : 1.f - q);

    const float has = (can_t > 0 && lms[k]) ? 1.f : 0.f;
    const int tgt = (can_t - 1) < 0 ? 0 : (can_t - 1);
    const float l0 = F[3*k], l1 = F[3*k+1], l2 = F[3*k+2];
    const float mx  = fmaxf(l0, fmaxf(l1, l2));
    const float lse = mx + __logf(__expf(l0 - mx) + __expf(l1 - mx) +
                                  __expf(l2 - mx));
    const float lt  = (tgt == 0) ? l0 : ((tgt == 1) ? l1 : l2);

    a0 += bf * m;
    a1 += m;
    a2 += (lse - lt) * has;
    a3 += has;
    a4 += bv * m;
  }

  // ---- write term (every thread owns exactly one row)
  const float a5 = fmaxf(wx, 0.f) - wx * wy + __logf(1.f + __expf(-fabsf(wx)));

  // ---- wave reduce, then block reduce via LDS
  float v[6] = {a0, a1, a2, a3, a4, a5};
  #pragma unroll
  for (int off = 32; off > 0; off >>= 1) {
    #pragma unroll
    for (int i = 0; i < 6; ++i) v[i] += __shfl_down(v[i], off, 64);
  }
  __shared__ float red[4][6];
  const int lane = tid & 63, w = tid >> 6;
  if (lane == 0) {
    #pragma unroll
    for (int i = 0; i < 6; ++i) red[w][i] = v[i];
  }
  __syncthreads();
  if (tid == 0) {
    #pragma unroll
    for (int i = 0; i < 6; ++i)
      part[blockIdx.x * 6 + i] = red[0][i] + red[1][i] + red[2][i] + red[3][i];
  }
}

// Reduce NBLK partials in double, compute the 5 outputs.
__global__ __launch_bounds__(BLOCK) void loss_finalize(
    const float* __restrict__ part, float* __restrict__ out)
{
  double v[6] = {0, 0, 0, 0, 0, 0};
  for (int r = threadIdx.x; r < NBLK; r += BLOCK) {
    #pragma unroll
    for (int i = 0; i < 6; ++i) v[i] += (double)part[r * 6 + i];
  }
  #pragma unroll
  for (int off = 32; off > 0; off >>= 1) {
    #pragma unroll
    for (int i = 0; i < 6; ++i) v[i] += __shfl_down(v[i], off, 64);
  }
  __shared__ double red[4][6];
  const int w = threadIdx.x >> 6, lane = threadIdx.x & 63;
  if (lane == 0) {
    #pragma unroll
    for (int i = 0; i < 6; ++i) red[w][i] = v[i];
  }
  __syncthreads();
  if (threadIdx.x == 0) {
    double a[6];
    #pragma unroll
    for (int i = 0; i < 6; ++i) a[i] = red[0][i] + red[1][i] + red[2][i] + red[3][i];
    const double live_n = a[1] < 1.0 ? 1.0 : a[1];
    const double fire   = a[0] / live_n;                                   // LAM_FIRE   = 1.0
    const double cancel = (a[3] > 0.0) ? a[2] / (a[3] < 1.0 ? 1.0 : a[3])  // LAM_CANCEL = 1.0
                                       : 0.0;
    const double valid  = 0.5 * a[4] / live_n;                             // LAM_VALID  = 0.5
    const double wr     = 0.5 * a[5] / (double)ROWS;                       // LAM_WRITE  = 0.5
    out[0] = (float)fire;
    out[1] = (float)cancel;
    out[2] = (float)valid;
    out[3] = (float)wr;
    out[4] = (float)(fire + cancel + valid + wr);
  }
}

extern "C" void kernel_launch(void* const* d_in, const int* in_sizes, int n_in,
                              void* d_out, int out_size, void* d_ws, size_t ws_size,
                              hipStream_t stream) {
  const float* trig   = (const float*)d_in[0];
  const float* valp   = (const float*)d_in[1];
  const float* clog   = (const float*)d_in[2];
  const float* wscore = (const float*)d_in[3];
  const int*   live   = (const int*)  d_in[4];
  const int*   cid    = (const int*)  d_in[5];
  const float* ofire  = (const float*)d_in[6];
  const int*   ocan   = (const int*)  d_in[7];
  const float* ovalid = (const float*)d_in[8];
  const float* oshw   = (const float*)d_in[9];
  const int*   ocid   = (const int*)  d_in[10];
  float* out  = (float*)d_out;
  float* part = (float*)d_ws;   // NBLK*6 floats = 24 KB, fully overwritten

  loss_main<<<NBLK, BLOCK, 0, stream>>>(trig, valp, clog, wscore, live, cid,
                                        ofire, ocan, ovalid, oshw, ocid, part);
  loss_finalize<<<1, BLOCK, 0, stream>>>(part, out);
}

// Round 7
// 212.124 us; speedup vs baseline: 1.0932x; 1.0932x over previous
//
#include <hip/hip_runtime.h>
#include <math.h>

#define EPS_F 1e-7f

constexpr int Bc = 32, Tc = 8192, Kc = 16;
constexpr int ROWS   = Bc * Tc;            // 262144 rows
constexpr int BLOCK  = 256;
constexpr int NITEM4 = ROWS * 4;           // 1048576 vec4 items (4 slots each)
constexpr int NBLK   = NITEM4 / BLOCK;     // 4096 blocks, 1 item per thread

typedef unsigned long long u64;

__device__ __forceinline__ u64 shflx64(u64 v, int m) {
  unsigned lo = __shfl_xor((unsigned)v, m, 64);
  unsigned hi = __shfl_xor((unsigned)(v >> 32), m, 64);
  return ((u64)hi << 32) | lo;
}

// Item-per-thread streaming: lane i owns vec4-item (base+i), so every load
// below is a dense 1KB/wave coalesced burst (clog: 3KB contiguous per wave
// at stride-48/lane -> same 3KB footprint, L1-absorbed). The per-row oracle
// first-match table is assembled with the PROVEN 4-lane shuffle merge from
// the R0/R2 kernel (benched absmax=0.0). No LDS staging (zero data reuse),
// no DMA pipeline, no barriers in the stream -> TLP (16 blocks/CU) + ILP
// carry the latency; coalescing fixes R4's 1.4x overfetch.
__global__ __launch_bounds__(BLOCK) void loss_main(
    const float* __restrict__ trig,
    const float* __restrict__ valp,
    const float* __restrict__ clog,
    const float* __restrict__ wscore,
    const int*   __restrict__ live,
    const int*   __restrict__ cid,
    const float* __restrict__ ofire,
    const int*   __restrict__ ocan,
    const float* __restrict__ ovalid,
    const float* __restrict__ oshw,
    const int*   __restrict__ ocid,
    float* __restrict__ part)            // [NBLK][6]
{
  const int tid  = threadIdx.x;
  const int lane = tid & 63;
  const int gi   = blockIdx.x * BLOCK + tid;      // my vec4 item
  const size_t o16 = (size_t)gi * 16;
  const size_t o48 = (size_t)gi * 48;

  // ---- coalesced register-direct loads (13 vec4 + 2 scalar per lane)
  const int4   oc = *(const int4*)  ((const char*)ocid   + o16);
  const int4   cc = *(const int4*)  ((const char*)ocan   + o16);
  const float4 ff = *(const float4*)((const char*)ofire  + o16);
  const float4 vv = *(const float4*)((const char*)ovalid + o16);
  const int4   cd = *(const int4*)  ((const char*)cid    + o16);
  const int4   lm = *(const int4*)  ((const char*)live   + o16);
  const float4 ph = *(const float4*)((const char*)trig   + o16);
  const float4 pq = *(const float4*)((const char*)valp   + o16);
  const float4 lA = *(const float4*)((const char*)clog   + o48 + 0);
  const float4 lB = *(const float4*)((const char*)clog   + o48 + 16);
  const float4 lC = *(const float4*)((const char*)clog   + o48 + 32);
  const int row = gi >> 2;
  const float wx = wscore[row];
  const float wy = oshw[row];

  // ---- per-lane partial oracle table (my 4 slots, slot order; first wins)
  u64 tblLo = 0ull, tblHi = 0ull, fndLo = 0ull, fndHi = 0ull;
  {
    const int   ocs[4] = {oc.x, oc.y, oc.z, oc.w};
    const int   ccs[4] = {cc.x, cc.y, cc.z, cc.w};
    const float ffs[4] = {ff.x, ff.y, ff.z, ff.w};
    const float vvs[4] = {vv.x, vv.y, vv.z, vv.w};
    #pragma unroll
    for (int j = 0; j < 4; ++j) {
      const unsigned c  = (unsigned)ocs[j] & 31u;
      const unsigned sh = (c & 15u) * 4u;
      const bool isLo   = c < 16u;
      const bool seen   = (((isLo ? fndLo : fndHi) >> sh) & 1ull) != 0ull;
      const unsigned nib = (unsigned)ffs[j] | ((unsigned)vvs[j] << 1) |
                           ((unsigned)ccs[j] << 2);
      const u64 add  = seen ? 0ull : ((u64)nib << sh);
      const u64 fadd = 0xFull << sh;
      tblLo |= isLo ? add : 0ull;
      tblHi |= isLo ? 0ull : add;
      fndLo |= isLo ? fadd : 0ull;
      fndHi |= isLo ? 0ull : fadd;
    }
  }

  // ---- merge across the 4-lane row group (lower lane = earlier slot wins)
  #pragma unroll
  for (int m = 1; m <= 2; m <<= 1) {
    const u64 pTL = shflx64(tblLo, m);
    const u64 pTH = shflx64(tblHi, m);
    const u64 pFL = shflx64(fndLo, m);
    const u64 pFH = shflx64(fndHi, m);
    const bool iLow = (lane & m) == 0;
    const u64 loTL = iLow ? tblLo : pTL, hiTL = iLow ? pTL : tblLo;
    const u64 loTH = iLow ? tblHi : pTH, hiTH = iLow ? pTH : tblHi;
    const u64 loFL = iLow ? fndLo : pFL, hiFL = iLow ? pFL : fndLo;
    const u64 loFH = iLow ? fndHi : pFH, hiFH = iLow ? pFH : fndHi;
    tblLo = loTL | (hiTL & ~loFL);
    tblHi = loTH | (hiTH & ~loFH);
    fndLo = loFL | hiFL;
    fndHi = loFH | hiFH;
  }

  // ---- losses for my 4 slots (proven compute path, unchanged)
  float a0 = 0.f, a1 = 0.f, a2 = 0.f, a3 = 0.f, a4 = 0.f;
  {
    const int   cds[4] = {cd.x, cd.y, cd.z, cd.w};
    const int   lms[4] = {lm.x, lm.y, lm.z, lm.w};
    const float phs[4] = {ph.x, ph.y, ph.z, ph.w};
    const float pqs[4] = {pq.x, pq.y, pq.z, pq.w};
    const float L0[4] = {lA.x, lA.w, lB.z, lC.y};
    const float L1[4] = {lA.y, lB.x, lB.w, lC.z};
    const float L2[4] = {lA.z, lB.y, lC.x, lC.w};
    #pragma unroll
    for (int j = 0; j < 4; ++j) {
      const unsigned c  = (unsigned)cds[j] & 31u;
      const unsigned sh = (c & 15u) * 4u;
      const bool isLo   = c < 16u;
      const bool fnd = (c != 0u) &&
                       ((((isLo ? fndLo : fndHi) >> sh) & 1ull) != 0ull);
      unsigned nib = (unsigned)(((isLo ? tblLo : tblHi) >> sh)) & 15u;
      nib = fnd ? nib : 0u;
      const float fire_t = (float)(nib & 1u);
      const float val_t  = (float)((nib >> 1) & 1u);
      const int   can_t  = (int)(nib >> 2);

      const float m = lms[j] ? 1.f : 0.f;

      const float p  = fminf(fmaxf(phs[j], EPS_F), 1.f - EPS_F);
      const float bf = -__logf((fire_t != 0.f) ? p : 1.f - p);
      const float q  = fminf(fmaxf(pqs[j], EPS_F), 1.f - EPS_F);
      const float bv = -__logf((val_t != 0.f) ? q : 1.f - q);

      const float has = (can_t > 0 && lms[j]) ? 1.f : 0.f;
      const int tgt = (can_t - 1) < 0 ? 0 : (can_t - 1);
      const float l0 = L0[j], l1 = L1[j], l2 = L2[j];
      const float mx  = fmaxf(l0, fmaxf(l1, l2));
      const float lse = mx + __logf(__expf(l0 - mx) + __expf(l1 - mx) +
                                    __expf(l2 - mx));
      const float lt  = (tgt == 0) ? l0 : ((tgt == 1) ? l1 : l2);

      a0 += bf * m;
      a1 += m;
      a2 += (lse - lt) * has;
      a3 += has;
      a4 += bv * m;
    }
  }

  // ---- write term (one lane per row adds it)
  float a5 = 0.f;
  if ((tid & 3) == 0) {
    a5 = fmaxf(wx, 0.f) - wx * wy + __logf(1.f + __expf(-fabsf(wx)));
  }

  // ---- wave reduce, then block reduce via LDS
  float v[6] = {a0, a1, a2, a3, a4, a5};
  #pragma unroll
  for (int off = 32; off > 0; off >>= 1) {
    #pragma unroll
    for (int i = 0; i < 6; ++i) v[i] += __shfl_down(v[i], off, 64);
  }
  __shared__ float red[4][6];
  const int w = tid >> 6;
  if (lane == 0) {
    #pragma unroll
    for (int i = 0; i < 6; ++i) red[w][i] = v[i];
  }
  __syncthreads();
  if (tid == 0) {
    #pragma unroll
    for (int i = 0; i < 6; ++i)
      part[blockIdx.x * 6 + i] = red[0][i] + red[1][i] + red[2][i] + red[3][i];
  }
}

// Reduce NBLK partials in double, compute the 5 outputs.
__global__ __launch_bounds__(BLOCK) void loss_finalize(
    const float* __restrict__ part, float* __restrict__ out)
{
  double v[6] = {0, 0, 0, 0, 0, 0};
  for (int r = threadIdx.x; r < NBLK; r += BLOCK) {
    #pragma unroll
    for (int i = 0; i < 6; ++i) v[i] += (double)part[r * 6 + i];
  }
  #pragma unroll
  for (int off = 32; off > 0; off >>= 1) {
    #pragma unroll
    for (int i = 0; i < 6; ++i) v[i] += __shfl_down(v[i], off, 64);
  }
  __shared__ double red[4][6];
  const int w = threadIdx.x >> 6, lane = threadIdx.x & 63;
  if (lane == 0) {
    #pragma unroll
    for (int i = 0; i < 6; ++i) red[w][i] = v[i];
  }
  __syncthreads();
  if (threadIdx.x == 0) {
    double a[6];
    #pragma unroll
    for (int i = 0; i < 6; ++i) a[i] = red[0][i] + red[1][i] + red[2][i] + red[3][i];
    const double live_n = a[1] < 1.0 ? 1.0 : a[1];
    const double fire   = a[0] / live_n;                                   // LAM_FIRE   = 1.0
    const double cancel = (a[3] > 0.0) ? a[2] / (a[3] < 1.0 ? 1.0 : a[3])  // LAM_CANCEL = 1.0
                                       : 0.0;
    const double valid  = 0.5 * a[4] / live_n;                             // LAM_VALID  = 0.5
    const double wr     = 0.5 * a[5] / (double)ROWS;                       // LAM_WRITE  = 0.5
    out[0] = (float)fire;
    out[1] = (float)cancel;
    out[2] = (float)valid;
    out[3] = (float)wr;
    out[4] = (float)(fire + cancel + valid + wr);
  }
}

extern "C" void kernel_launch(void* const* d_in, const int* in_sizes, int n_in,
                              void* d_out, int out_size, void* d_ws, size_t ws_size,
                              hipStream_t stream) {
  const float* trig   = (const float*)d_in[0];
  const float* valp   = (const float*)d_in[1];
  const float* clog   = (const float*)d_in[2];
  const float* wscore = (const float*)d_in[3];
  const int*   live   = (const int*)  d_in[4];
  const int*   cid    = (const int*)  d_in[5];
  const float* ofire  = (const float*)d_in[6];
  const int*   ocan   = (const int*)  d_in[7];
  const float* ovalid = (const float*)d_in[8];
  const float* oshw   = (const float*)d_in[9];
  const int*   ocid   = (const int*)  d_in[10];
  float* out  = (float*)d_out;
  float* part = (float*)d_ws;   // NBLK*6 floats = 96 KB, fully overwritten

  loss_main<<<NBLK, BLOCK, 0, stream>>>(trig, valp, clog, wscore, live, cid,
                                        ofire, ocan, ovalid, oshw, ocid, part);
  loss_finalize<<<1, BLOCK, 0, stream>>>(part, out);
}

// Round 8
// 210.905 us; speedup vs baseline: 1.0995x; 1.0058x over previous
//
#include <hip/hip_runtime.h>
#include <math.h>

#define EPS_F 1e-7f

constexpr int Bc = 32, Tc = 8192, Kc = 16;
constexpr int ROWS   = Bc * Tc;            // 262144 rows
constexpr int BLOCK  = 256;
constexpr int NITEM4 = ROWS * 4;           // 1048576 vec4 items (4 slots each)
constexpr int NBLK   = NITEM4 / BLOCK;     // 4096 blocks, 1 item per thread

typedef unsigned long long u64;

__device__ __forceinline__ u64 shflx64(u64 v, int m) {
  unsigned lo = __shfl_xor((unsigned)v, m, 64);
  unsigned hi = __shfl_xor((unsigned)(v >> 32), m, 64);
  return ((u64)hi << 32) | lo;
}

// Keep-alive pins: force the loaded values to be materialized in VGPRs at
// this point, ALL SIMULTANEOUSLY LIVE (pins are consecutive). This prevents
// the R7 failure mode where the compiler allocated 28 VGPRs and chunked the
// 13-load burst into serialized load->wait->consume groups (latency-bound,
// ~1KB/wave in flight). With the pins, all 13 loads issue in one burst and
// a single vmcnt wait precedes the compute. [rule #17 keep-alive primitive]
#define PIN_I4(v) asm volatile("" :: "v"((v).x), "v"((v).y), "v"((v).z), "v"((v).w))
#define PIN_F4(v) asm volatile("" :: "v"((v).x), "v"((v).y), "v"((v).z), "v"((v).w))
#define PIN_F(v)  asm volatile("" :: "v"(v))

// Item-per-thread streaming: lane i owns vec4-item (base+i), so every load
// below is a dense 1KB/wave coalesced burst (clog: 3KB contiguous per wave).
// Proven compute path (absmax=0.0 in R2/R4/R7). No LDS staging, no barriers
// in the stream; TLP + full-burst ILP carry the HBM/L3 latency.
__global__ __launch_bounds__(BLOCK) void loss_main(
    const float* __restrict__ trig,
    const float* __restrict__ valp,
    const float* __restrict__ clog,
    const float* __restrict__ wscore,
    const int*   __restrict__ live,
    const int*   __restrict__ cid,
    const float* __restrict__ ofire,
    const int*   __restrict__ ocan,
    const float* __restrict__ ovalid,
    const float* __restrict__ oshw,
    const int*   __restrict__ ocid,
    float* __restrict__ part)            // [NBLK][6]
{
  const int tid  = threadIdx.x;
  const int lane = tid & 63;
  const int gi   = blockIdx.x * BLOCK + tid;      // my vec4 item
  const size_t o16 = (size_t)gi * 16;
  const size_t o48 = (size_t)gi * 48;

  // ---- coalesced register-direct loads (13 vec4 + 2 scalar per lane)
  const int4   oc = *(const int4*)  ((const char*)ocid   + o16);
  const int4   cc = *(const int4*)  ((const char*)ocan   + o16);
  const float4 ff = *(const float4*)((const char*)ofire  + o16);
  const float4 vv = *(const float4*)((const char*)ovalid + o16);
  const int4   cd = *(const int4*)  ((const char*)cid    + o16);
  const int4   lm = *(const int4*)  ((const char*)live   + o16);
  const float4 ph = *(const float4*)((const char*)trig   + o16);
  const float4 pq = *(const float4*)((const char*)valp   + o16);
  const float4 lA = *(const float4*)((const char*)clog   + o48 + 0);
  const float4 lB = *(const float4*)((const char*)clog   + o48 + 16);
  const float4 lC = *(const float4*)((const char*)clog   + o48 + 32);
  const int row = gi >> 2;
  const float wx = wscore[row];
  const float wy = oshw[row];

  // ---- pin block: all 54 loaded scalars live at once -> one load burst
  PIN_I4(oc); PIN_I4(cc); PIN_F4(ff); PIN_F4(vv);
  PIN_I4(cd); PIN_I4(lm); PIN_F4(ph); PIN_F4(pq);
  PIN_F4(lA); PIN_F4(lB); PIN_F4(lC);
  PIN_F(wx);  PIN_F(wy);

  // ---- per-lane partial oracle table (my 4 slots, slot order; first wins)
  u64 tblLo = 0ull, tblHi = 0ull, fndLo = 0ull, fndHi = 0ull;
  {
    const int   ocs[4] = {oc.x, oc.y, oc.z, oc.w};
    const int   ccs[4] = {cc.x, cc.y, cc.z, cc.w};
    const float ffs[4] = {ff.x, ff.y, ff.z, ff.w};
    const float vvs[4] = {vv.x, vv.y, vv.z, vv.w};
    #pragma unroll
    for (int j = 0; j < 4; ++j) {
      const unsigned c  = (unsigned)ocs[j] & 31u;
      const unsigned sh = (c & 15u) * 4u;
      const bool isLo   = c < 16u;
      const bool seen   = (((isLo ? fndLo : fndHi) >> sh) & 1ull) != 0ull;
      const unsigned nib = (unsigned)ffs[j] | ((unsigned)vvs[j] << 1) |
                           ((unsigned)ccs[j] << 2);
      const u64 add  = seen ? 0ull : ((u64)nib << sh);
      const u64 fadd = 0xFull << sh;
      tblLo |= isLo ? add : 0ull;
      tblHi |= isLo ? 0ull : add;
      fndLo |= isLo ? fadd : 0ull;
      fndHi |= isLo ? 0ull : fadd;
    }
  }

  // ---- merge across the 4-lane row group (lower lane = earlier slot wins)
  #pragma unroll
  for (int m = 1; m <= 2; m <<= 1) {
    const u64 pTL = shflx64(tblLo, m);
    const u64 pTH = shflx64(tblHi, m);
    const u64 pFL = shflx64(fndLo, m);
    const u64 pFH = shflx64(fndHi, m);
    const bool iLow = (lane & m) == 0;
    const u64 loTL = iLow ? tblLo : pTL, hiTL = iLow ? pTL : tblLo;
    const u64 loTH = iLow ? tblHi : pTH, hiTH = iLow ? pTH : tblHi;
    const u64 loFL = iLow ? fndLo : pFL, hiFL = iLow ? pFL : fndLo;
    const u64 loFH = iLow ? fndHi : pFH, hiFH = iLow ? pFH : fndHi;
    tblLo = loTL | (hiTL & ~loFL);
    tblHi = loTH | (hiTH & ~loFH);
    fndLo = loFL | hiFL;
    fndHi = loFH | hiFH;
  }

  // ---- losses for my 4 slots (proven compute path, unchanged)
  float a0 = 0.f, a1 = 0.f, a2 = 0.f, a3 = 0.f, a4 = 0.f;
  {
    const int   cds[4] = {cd.x, cd.y, cd.z, cd.w};
    const int   lms[4] = {lm.x, lm.y, lm.z, lm.w};
    const float phs[4] = {ph.x, ph.y, ph.z, ph.w};
    const float pqs[4] = {pq.x, pq.y, pq.z, pq.w};
    const float L0[4] = {lA.x, lA.w, lB.z, lC.y};
    const float L1[4] = {lA.y, lB.x, lB.w, lC.z};
    const float L2[4] = {lA.z, lB.y, lC.x, lC.w};
    #pragma unroll
    for (int j = 0; j < 4; ++j) {
      const unsigned c  = (unsigned)cds[j] & 31u;
      const unsigned sh = (c & 15u) * 4u;
      const bool isLo   = c < 16u;
      const bool fnd = (c != 0u) &&
                       ((((isLo ? fndLo : fndHi) >> sh) & 1ull) != 0ull);
      unsigned nib = (unsigned)(((isLo ? tblLo : tblHi) >> sh)) & 15u;
      nib = fnd ? nib : 0u;
      const float fire_t = (float)(nib & 1u);
      const float val_t  = (float)((nib >> 1) & 1u);
      const int   can_t  = (int)(nib >> 2);

      const float m = lms[j] ? 1.f : 0.f;

      const float p  = fminf(fmaxf(phs[j], EPS_F), 1.f - EPS_F);
      const float bf = -__logf((fire_t != 0.f) ? p : 1.f - p);
      const float q  = fminf(fmaxf(pqs[j], EPS_F), 1.f - EPS_F);
      const float bv = -__logf((val_t != 0.f) ? q : 1.f - q);

      const float has = (can_t > 0 && lms[j]) ? 1.f : 0.f;
      const int tgt = (can_t - 1) < 0 ? 0 : (can_t - 1);
      const float l0 = L0[j], l1 = L1[j], l2 = L2[j];
      const float mx  = fmaxf(l0, fmaxf(l1, l2));
      const float lse = mx + __logf(__expf(l0 - mx) + __expf(l1 - mx) +
                                    __expf(l2 - mx));
      const float lt  = (tgt == 0) ? l0 : ((tgt == 1) ? l1 : l2);

      a0 += bf * m;
      a1 += m;
      a2 += (lse - lt) * has;
      a3 += has;
      a4 += bv * m;
    }
  }

  // ---- write term (one lane per row adds it)
  float a5 = 0.f;
  if ((tid & 3) == 0) {
    a5 = fmaxf(wx, 0.f) - wx * wy + __logf(1.f + __expf(-fabsf(wx)));
  }

  // ---- wave reduce, then block reduce via LDS
  float v[6] = {a0, a1, a2, a3, a4, a5};
  #pragma unroll
  for (int off = 32; off > 0; off >>= 1) {
    #pragma unroll
    for (int i = 0; i < 6; ++i) v[i] += __shfl_down(v[i], off, 64);
  }
  __shared__ float red[4][6];
  const int w = tid >> 6;
  if (lane == 0) {
    #pragma unroll
    for (int i = 0; i < 6; ++i) red[w][i] = v[i];
  }
  __syncthreads();
  if (tid == 0) {
    #pragma unroll
    for (int i = 0; i < 6; ++i)
      part[blockIdx.x * 6 + i] = red[0][i] + red[1][i] + red[2][i] + red[3][i];
  }
}

// Reduce NBLK partials in double, compute the 5 outputs.
__global__ __launch_bounds__(BLOCK) void loss_finalize(
    const float* __restrict__ part, float* __restrict__ out)
{
  double v[6] = {0, 0, 0, 0, 0, 0};
  for (int r = threadIdx.x; r < NBLK; r += BLOCK) {
    #pragma unroll
    for (int i = 0; i < 6; ++i) v[i] += (double)part[r * 6 + i];
  }
  #pragma unroll
  for (int off = 32; off > 0; off >>= 1) {
    #pragma unroll
    for (int i = 0; i < 6; ++i) v[i] += __shfl_down(v[i], off, 64);
  }
  __shared__ double red[4][6];
  const int w = threadIdx.x >> 6, lane = threadIdx.x & 63;
  if (lane == 0) {
    #pragma unroll
    for (int i = 0; i < 6; ++i) red[w][i] = v[i];
  }
  __syncthreads();
  if (threadIdx.x == 0) {
    double a[6];
    #pragma unroll
    for (int i = 0; i < 6; ++i) a[i] = red[0][i] + red[1][i] + red[2][i] + red[3][i];
    const double live_n = a[1] < 1.0 ? 1.0 : a[1];
    const double fire   = a[0] / live_n;                                   // LAM_FIRE   = 1.0
    const double cancel = (a[3] > 0.0) ? a[2] / (a[3] < 1.0 ? 1.0 : a[3])  // LAM_CANCEL = 1.0
                                       : 0.0;
    const double valid  = 0.5 * a[4] / live_n;                             // LAM_VALID  = 0.5
    const double wr     = 0.5 * a[5] / (double)ROWS;                       // LAM_WRITE  = 0.5
    out[0] = (float)fire;
    out[1] = (float)cancel;
    out[2] = (float)valid;
    out[3] = (float)wr;
    out[4] = (float)(fire + cancel + valid + wr);
  }
}

extern "C" void kernel_launch(void* const* d_in, const int* in_sizes, int n_in,
                              void* d_out, int out_size, void* d_ws, size_t ws_size,
                              hipStream_t stream) {
  const float* trig   = (const float*)d_in[0];
  const float* valp   = (const float*)d_in[1];
  const float* clog   = (const float*)d_in[2];
  const float* wscore = (const float*)d_in[3];
  const int*   live   = (const int*)  d_in[4];
  const int*   cid    = (const int*)  d_in[5];
  const float* ofire  = (const float*)d_in[6];
  const int*   ocan   = (const int*)  d_in[7];
  const float* ovalid = (const float*)d_in[8];
  const float* oshw   = (const float*)d_in[9];
  const int*   ocid   = (const int*)  d_in[10];
  float* out  = (float*)d_out;
  float* part = (float*)d_ws;   // NBLK*6 floats = 96 KB, fully overwritten

  loss_main<<<NBLK, BLOCK, 0, stream>>>(trig, valp, clog, wscore, live, cid,
                                        ofire, ocan, ovalid, oshw, ocid, part);
  loss_finalize<<<1, BLOCK, 0, stream>>>(part, out);
}